// Round 1
// baseline (2219.901 us; speedup 1.0000x reference)
//
#include <hip/hip_runtime.h>

#define NN 100000
#define NE 3200000
#define FEAT 128
#define EMBED 128

// ---------------------------------------------------------------------------
// h[n][e] = sum_f x[n][f] * w[e][f]
// Block: 256 threads -> 64 rows, full 128-embed width.
// W staged in LDS padded [128][132] floats; read order rotated by eg to kill
// bank conflicts. X read from global (L1 broadcast across eg-groups).
// Thread (eg = t&15, rg = t>>4): rows {rg, rg+16, rg+32, rg+48}, e in [eg*8, eg*8+8).
// ---------------------------------------------------------------------------
__global__ __launch_bounds__(256, 2)
void gemm_xwT(const float* __restrict__ x, const float* __restrict__ w,
              float* __restrict__ h, int n_nodes) {
    __shared__ float4 w_lds[128 * 33];  // 132 floats per row (pad 4) = 67.6 KB
    int t = threadIdx.x;
    const float4* w4 = (const float4*)w;
    for (int i = t; i < 128 * 32; i += 256) {
        int e = i >> 5, fc = i & 31;
        w_lds[e * 33 + fc] = w4[i];
    }
    __syncthreads();

    int eg = t & 15, rg = t >> 4;
    int e0 = eg * 8;
    long row0 = (long)blockIdx.x * 64;
    int rows_left = n_nodes - (int)row0;
    const float4* x4 = (const float4*)x;  // [row*32 + fc]

    float acc[4][8];
#pragma unroll
    for (int r = 0; r < 4; ++r)
#pragma unroll
        for (int j = 0; j < 8; ++j) acc[r][j] = 0.f;

#pragma unroll 2
    for (int fc = 0; fc < 32; ++fc) {
        float4 xv[4];
#pragma unroll
        for (int r = 0; r < 4; ++r) {
            int rr = rg + 16 * r;
            int rc = rr < rows_left ? rr : 0;  // clamp; result unused if OOB
            xv[r] = x4[(row0 + rc) * 32 + fc];
        }
#pragma unroll
        for (int j = 0; j < 8; ++j) {
            int jj = (j + eg) & 7;  // rotate read order -> conflict-free banks
            float4 wv = w_lds[(e0 + jj) * 33 + fc];
#pragma unroll
            for (int r = 0; r < 4; ++r) {
                acc[r][jj] += xv[r].x * wv.x + xv[r].y * wv.y +
                              xv[r].z * wv.z + xv[r].w * wv.w;
            }
        }
    }

#pragma unroll
    for (int r = 0; r < 4; ++r) {
        int rr = rg + 16 * r;
        if (rr < rows_left) {
            float4* hp = (float4*)(h + (row0 + rr) * 128);
            hp[eg * 2 + 0] = make_float4(acc[r][0], acc[r][1], acc[r][2], acc[r][3]);
            hp[eg * 2 + 1] = make_float4(acc[r][4], acc[r][5], acc[r][6], acc[r][7]);
        }
    }
}

// ---------------------------------------------------------------------------
// CSR row offsets from sorted edge_dst via per-node lower_bound.
// rowptr[n] = first edge index with dst >= n; rowptr[NN] = NE.
// ---------------------------------------------------------------------------
__global__ void build_rowptr(const int* __restrict__ dst, int* __restrict__ rowptr) {
    int n = blockIdx.x * blockDim.x + threadIdx.x;
    if (n > NN) return;
    int lo = 0, hi = NE;
    while (lo < hi) {
        int mid = (lo + hi) >> 1;
        if (dst[mid] < n) lo = mid + 1; else hi = mid;
    }
    rowptr[n] = lo;
}

// ---------------------------------------------------------------------------
// One wave per destination node. Lane holds float2 of the 128-dim row.
// Edge metadata preloaded 64-wide coalesced, broadcast via shfl.
// Each out row written exactly once (covers poisoned d_out, no memset needed).
// ---------------------------------------------------------------------------
__global__ __launch_bounds__(256)
void aggregate(const float* __restrict__ h, const float* __restrict__ ew,
               const int* __restrict__ src, const int* __restrict__ rowptr,
               float* __restrict__ out) {
    int wid = (int)((blockIdx.x * (unsigned)blockDim.x + threadIdx.x) >> 6);
    int lane = threadIdx.x & 63;
    if (wid >= NN) return;
    int start = rowptr[wid];
    int end = rowptr[wid + 1];

    float accx = 0.f, accy = 0.f;
    for (int base = start; base < end; base += 64) {
        int cnt = min(64, end - base);
        int s = 0; float wv = 0.f;
        if (lane < cnt) {
            s = src[base + lane];
            wv = ew[base + lane];
        }
#pragma unroll 4
        for (int i = 0; i < cnt; ++i) {
            int si = __shfl(s, i);
            float wi = __shfl(wv, i);
            float2 v = *(const float2*)(h + (long)si * 128 + lane * 2);
            accx += wi * v.x;
            accy += wi * v.y;
        }
    }
    float2* op = (float2*)(out + (long)wid * 128 + lane * 2);
    *op = make_float2(accx, accy);
}

extern "C" void kernel_launch(void* const* d_in, const int* in_sizes, int n_in,
                              void* d_out, int out_size, void* d_ws, size_t ws_size,
                              hipStream_t stream) {
    const float* x    = (const float*)d_in[0];
    const float* w    = (const float*)d_in[1];
    const float* ew   = (const float*)d_in[2];
    const int*   esrc = (const int*)d_in[3];
    const int*   edst = (const int*)d_in[4];
    float* out = (float*)d_out;

    float* h = (float*)d_ws;                                   // 51.2 MB
    int* rowptr = (int*)((char*)d_ws + (size_t)NN * 128 * 4);  // +400 KB

    gemm_xwT<<<(NN + 63) / 64, 256, 0, stream>>>(x, w, h, NN);
    build_rowptr<<<(NN + 1 + 255) / 256, 256, 0, stream>>>(edst, rowptr);
    aggregate<<<(NN * 64) / 256, 256, 0, stream>>>(h, ew, esrc, rowptr, out);
}

// Round 2
// 364.195 us; speedup vs baseline: 6.0954x; 6.0954x over previous
//
#include <hip/hip_runtime.h>

#define NN 100000
#define NE 3200000
#define FEAT 128
#define EMBED 128

// ---------------------------------------------------------------------------
// h[n][e] = sum_f x[n][f] * w[e][f]
// Block: 256 threads -> 64 rows x full 128-embed width.
// Thread (rg = t&15, eg = t>>4): rows {rg, rg+16, rg+32, rg+48},
//   embeds [eg*8, eg*8+8).
// W staged in LDS, XOR-swizzled: w_lds[e*32 + (fc ^ (e>>3))].
//   Read at (e0+j): idx = (e0+j)*32 + (fc ^ eg) -> within a wave the 4
//   distinct eg values map to 4 distinct 16B bank slots (conflict-free),
//   16 lanes sharing each address broadcast for free.
// ALL accumulator indices are compile-time constants (rule #20: runtime-
// indexed arrays go to scratch -- this was R0's 100x bug).
// ---------------------------------------------------------------------------
__global__ __launch_bounds__(256, 2)
void gemm_xwT(const float* __restrict__ x, const float* __restrict__ w,
              float* __restrict__ h, int n_nodes) {
    __shared__ float4 w_lds[128 * 32];  // 64 KB, XOR-swizzled, no pad
    int t = threadIdx.x;
    const float4* w4 = (const float4*)w;
    for (int i = t; i < 128 * 32; i += 256) {
        int e = i >> 5, fc = i & 31;
        w_lds[e * 32 + (fc ^ (e >> 3))] = w4[i];
    }
    __syncthreads();

    int rg = t & 15, eg = t >> 4;
    int e0 = eg * 8;
    long row0 = (long)blockIdx.x * 64;
    int rows_left = n_nodes - (int)row0;
    const float4* x4 = (const float4*)x;  // [row*32 + fc]

    float acc[4][8];
#pragma unroll
    for (int r = 0; r < 4; ++r)
#pragma unroll
        for (int j = 0; j < 8; ++j) acc[r][j] = 0.f;

#pragma unroll 4
    for (int fc = 0; fc < 32; ++fc) {
        float4 xv[4];
#pragma unroll
        for (int r = 0; r < 4; ++r) {
            int rr = rg + 16 * r;
            int rc = rr < rows_left ? rr : 0;  // clamp; result unused if OOB
            xv[r] = x4[(row0 + rc) * 32 + fc];
        }
#pragma unroll
        for (int j = 0; j < 8; ++j) {
            float4 wv = w_lds[(e0 + j) * 32 + (fc ^ eg)];
#pragma unroll
            for (int r = 0; r < 4; ++r) {
                acc[r][j] += xv[r].x * wv.x + xv[r].y * wv.y +
                             xv[r].z * wv.z + xv[r].w * wv.w;
            }
        }
    }

#pragma unroll
    for (int r = 0; r < 4; ++r) {
        int rr = rg + 16 * r;
        if (rr < rows_left) {
            float4* hp = (float4*)(h + (row0 + rr) * 128);
            hp[eg * 2 + 0] = make_float4(acc[r][0], acc[r][1], acc[r][2], acc[r][3]);
            hp[eg * 2 + 1] = make_float4(acc[r][4], acc[r][5], acc[r][6], acc[r][7]);
        }
    }
}

// ---------------------------------------------------------------------------
// CSR row offsets from sorted edge_dst via per-node lower_bound.
// rowptr[n] = first edge index with dst >= n; rowptr[NN] = NE.
// ---------------------------------------------------------------------------
__global__ void build_rowptr(const int* __restrict__ dst, int* __restrict__ rowptr) {
    int n = blockIdx.x * blockDim.x + threadIdx.x;
    if (n > NN) return;
    int lo = 0, hi = NE;
    while (lo < hi) {
        int mid = (lo + hi) >> 1;
        if (dst[mid] < n) lo = mid + 1; else hi = mid;
    }
    rowptr[n] = lo;
}

// ---------------------------------------------------------------------------
// One wave per destination node. Lane holds float2 of the 128-dim row.
// Edge metadata preloaded 64-wide coalesced, broadcast via shfl.
// Each out row written exactly once (covers poisoned d_out, no memset needed).
// ---------------------------------------------------------------------------
__global__ __launch_bounds__(256)
void aggregate(const float* __restrict__ h, const float* __restrict__ ew,
               const int* __restrict__ src, const int* __restrict__ rowptr,
               float* __restrict__ out) {
    int wid = (int)((blockIdx.x * (unsigned)blockDim.x + threadIdx.x) >> 6);
    int lane = threadIdx.x & 63;
    if (wid >= NN) return;
    int start = rowptr[wid];
    int end = rowptr[wid + 1];

    float accx = 0.f, accy = 0.f;
    for (int base = start; base < end; base += 64) {
        int cnt = min(64, end - base);
        int s = 0; float wv = 0.f;
        if (lane < cnt) {
            s = src[base + lane];
            wv = ew[base + lane];
        }
#pragma unroll 4
        for (int i = 0; i < cnt; ++i) {
            int si = __shfl(s, i);
            float wi = __shfl(wv, i);
            float2 v = *(const float2*)(h + (long)si * 128 + lane * 2);
            accx += wi * v.x;
            accy += wi * v.y;
        }
    }
    float2* op = (float2*)(out + (long)wid * 128 + lane * 2);
    *op = make_float2(accx, accy);
}

extern "C" void kernel_launch(void* const* d_in, const int* in_sizes, int n_in,
                              void* d_out, int out_size, void* d_ws, size_t ws_size,
                              hipStream_t stream) {
    const float* x    = (const float*)d_in[0];
    const float* w    = (const float*)d_in[1];
    const float* ew   = (const float*)d_in[2];
    const int*   esrc = (const int*)d_in[3];
    const int*   edst = (const int*)d_in[4];
    float* out = (float*)d_out;

    float* h = (float*)d_ws;                                   // 51.2 MB
    int* rowptr = (int*)((char*)d_ws + (size_t)NN * 128 * 4);  // +400 KB

    gemm_xwT<<<(NN + 63) / 64, 256, 0, stream>>>(x, w, h, NN);
    build_rowptr<<<(NN + 1 + 255) / 256, 256, 0, stream>>>(edst, rowptr);
    aggregate<<<(NN * 64) / 256, 256, 0, stream>>>(h, ew, esrc, rowptr, out);
}

// Round 3
// 234.420 us; speedup vs baseline: 9.4698x; 1.5536x over previous
//
#include <hip/hip_runtime.h>

#define NN 100000
#define NE 3200000
#define FEAT 128
#define EMBED 128

typedef __attribute__((ext_vector_type(8))) __bf16 bf16x8;
typedef __attribute__((ext_vector_type(8))) unsigned short ushort8;
typedef __attribute__((ext_vector_type(4))) float f32x4;

static __device__ __forceinline__ unsigned short f2bf(float f) {
    unsigned u = __float_as_uint(f);
    return (unsigned short)((u + 0x7FFFu + ((u >> 16) & 1u)) >> 16);  // RNE
}

// ---------------------------------------------------------------------------
// w fp32 [128][128] -> bf16 bits (ushort) [128][128]
// ---------------------------------------------------------------------------
__global__ void convert_w(const float* __restrict__ w, unsigned short* __restrict__ wbf) {
    int i = blockIdx.x * 256 + threadIdx.x;
    if (i < EMBED * FEAT) wbf[i] = f2bf(w[i]);
}

// ---------------------------------------------------------------------------
// h_bf[n][e] = bf16( sum_f x[n][f] * w[e][f] ), via mfma_f32_16x16x32_bf16.
// One wave per 16-row stripe; 8 col-tiles x 4 k-steps = 32 MFMA/wave.
// A: lane l holds x[row0 + (l&15)][ks*32 + (l>>4)*8 .. +7] (fp32->bf16 in reg)
// B: lane l holds w[nt*16 + (l&15)][ks*32 + (l>>4)*8 .. +7] (w is [N][K] row-major)
// D: col = l&15, row = (l>>4)*4 + reg   [verified layout, learn_hip m89]
// No LDS; B fragments read from 32 KB w_bf (L1/L2-resident).
// ---------------------------------------------------------------------------
__global__ __launch_bounds__(256)
void gemm_xwT(const float* __restrict__ x, const unsigned short* __restrict__ wbf,
              unsigned short* __restrict__ hbf) {
    int wave = blockIdx.x * 4 + (threadIdx.x >> 6);
    long row0 = (long)wave * 16;
    if (row0 >= NN) return;
    int lane = threadIdx.x & 63;
    int r = lane & 15, kg = lane >> 4;

    const float4* x4 = (const float4*)x;  // [row*32 + fc4]
    const bf16x8* wb = (const bf16x8*)wbf;

    // Load + convert A fragments (32 floats/lane total)
    bf16x8 afr[4];
#pragma unroll
    for (int ks = 0; ks < 4; ++ks) {
        long base = (row0 + r) * 32 + ks * 8 + kg * 2;
        float4 v0 = x4[base];
        float4 v1 = x4[base + 1];
        float xf[8] = {v0.x, v0.y, v0.z, v0.w, v1.x, v1.y, v1.z, v1.w};
        ushort8 au;
#pragma unroll
        for (int e = 0; e < 8; ++e) au[e] = f2bf(xf[e]);
        afr[ks] = __builtin_bit_cast(bf16x8, au);
    }

    f32x4 acc[8];
#pragma unroll
    for (int nt = 0; nt < 8; ++nt) acc[nt] = (f32x4){0.f, 0.f, 0.f, 0.f};

#pragma unroll
    for (int nt = 0; nt < 8; ++nt) {
#pragma unroll
        for (int ks = 0; ks < 4; ++ks) {
            bf16x8 b = wb[(nt * 16 + r) * 16 + ks * 4 + kg];
            acc[nt] = __builtin_amdgcn_mfma_f32_16x16x32_bf16(afr[ks], b, acc[nt], 0, 0, 0);
        }
    }

    // Store: row = row0 + kg*4 + reg, col = nt*16 + r
#pragma unroll
    for (int nt = 0; nt < 8; ++nt) {
#pragma unroll
        for (int reg = 0; reg < 4; ++reg) {
            hbf[(row0 + kg * 4 + reg) * 128 + nt * 16 + r] = f2bf(acc[nt][reg]);
        }
    }
}

// ---------------------------------------------------------------------------
// CSR row offsets from sorted edge_dst via per-node lower_bound.
// ---------------------------------------------------------------------------
__global__ void build_rowptr(const int* __restrict__ dst, int* __restrict__ rowptr) {
    int n = blockIdx.x * blockDim.x + threadIdx.x;
    if (n > NN) return;
    int lo = 0, hi = NE;
    while (lo < hi) {
        int mid = (lo + hi) >> 1;
        if (dst[mid] < n) lo = mid + 1; else hi = mid;
    }
    rowptr[n] = lo;
}

// ---------------------------------------------------------------------------
// One wave per destination node. h is bf16: lane gathers 1 dword = 2 bf16 cols
// (256 B/wave/edge). Accumulate fp32, write out fp32 float2 per lane.
// Each out row written exactly once (covers poisoned d_out).
// ---------------------------------------------------------------------------
__global__ __launch_bounds__(256)
void aggregate(const unsigned int* __restrict__ h32, const float* __restrict__ ew,
               const int* __restrict__ src, const int* __restrict__ rowptr,
               float* __restrict__ out) {
    int wid = (int)((blockIdx.x * (unsigned)blockDim.x + threadIdx.x) >> 6);
    int lane = threadIdx.x & 63;
    if (wid >= NN) return;
    int start = rowptr[wid];
    int end = rowptr[wid + 1];

    float accx = 0.f, accy = 0.f;
    for (int base = start; base < end; base += 64) {
        int cnt = min(64, end - base);
        int s = 0; float wv = 0.f;
        if (lane < cnt) {
            s = src[base + lane];
            wv = ew[base + lane];
        }
#pragma unroll 8
        for (int i = 0; i < cnt; ++i) {
            int si = __shfl(s, i);
            float wi = __shfl(wv, i);
            unsigned u = h32[(long)si * 64 + lane];
            accx += wi * __uint_as_float(u << 16);
            accy += wi * __uint_as_float(u & 0xFFFF0000u);
        }
    }
    float2* op = (float2*)(out + (long)wid * 128 + lane * 2);
    *op = make_float2(accx, accy);
}

extern "C" void kernel_launch(void* const* d_in, const int* in_sizes, int n_in,
                              void* d_out, int out_size, void* d_ws, size_t ws_size,
                              hipStream_t stream) {
    const float* x    = (const float*)d_in[0];
    const float* w    = (const float*)d_in[1];
    const float* ew   = (const float*)d_in[2];
    const int*   esrc = (const int*)d_in[3];
    const int*   edst = (const int*)d_in[4];
    float* out = (float*)d_out;

    unsigned short* hbf = (unsigned short*)d_ws;                       // 25.6 MB
    int* rowptr = (int*)((char*)d_ws + (size_t)NN * 128 * 2);          // +400 KB
    unsigned short* wbf = (unsigned short*)((char*)d_ws + (size_t)NN * 128 * 2 + 400016);

    convert_w<<<64, 256, 0, stream>>>(w, wbf);
    gemm_xwT<<<(NN / 16 + 3) / 4, 256, 0, stream>>>(x, wbf, hbf);
    build_rowptr<<<(NN + 1 + 255) / 256, 256, 0, stream>>>(edst, rowptr);
    aggregate<<<(NN * 64) / 256, 256, 0, stream>>>((const unsigned int*)hbf, ew, esrc, rowptr, out);
}

// Round 4
// 167.271 us; speedup vs baseline: 13.2713x; 1.4014x over previous
//
#include <hip/hip_runtime.h>

#define NN 100000
#define NE 3200000
#define FEAT 128
#define EMBED 128

typedef __attribute__((ext_vector_type(8))) __bf16 bf16x8;
typedef __attribute__((ext_vector_type(8))) unsigned short ushort8;
typedef __attribute__((ext_vector_type(4))) float f32x4;

static __device__ __forceinline__ unsigned short f2bf(float f) {
    unsigned u = __float_as_uint(f);
    return (unsigned short)((u + 0x7FFFu + ((u >> 16) & 1u)) >> 16);  // RNE
}

// ---------------------------------------------------------------------------
// w fp32 [128][128] -> bf16 bits (ushort) [128][128]
// ---------------------------------------------------------------------------
__global__ void convert_w(const float* __restrict__ w, unsigned short* __restrict__ wbf) {
    int i = blockIdx.x * 256 + threadIdx.x;
    if (i < EMBED * FEAT) wbf[i] = f2bf(w[i]);
}

// ---------------------------------------------------------------------------
// h_bf[n][e] = bf16( sum_f x[n][f] * w[e][f] ), via mfma_f32_16x16x32_bf16.
// (unchanged from R2 -- memory-bound, passing)
// ---------------------------------------------------------------------------
__global__ __launch_bounds__(256)
void gemm_xwT(const float* __restrict__ x, const unsigned short* __restrict__ wbf,
              unsigned short* __restrict__ hbf) {
    int wave = blockIdx.x * 4 + (threadIdx.x >> 6);
    long row0 = (long)wave * 16;
    if (row0 >= NN) return;
    int lane = threadIdx.x & 63;
    int r = lane & 15, kg = lane >> 4;

    const float4* x4 = (const float4*)x;  // [row*32 + fc4]
    const bf16x8* wb = (const bf16x8*)wbf;

    bf16x8 afr[4];
#pragma unroll
    for (int ks = 0; ks < 4; ++ks) {
        long base = (row0 + r) * 32 + ks * 8 + kg * 2;
        float4 v0 = x4[base];
        float4 v1 = x4[base + 1];
        float xf[8] = {v0.x, v0.y, v0.z, v0.w, v1.x, v1.y, v1.z, v1.w};
        ushort8 au;
#pragma unroll
        for (int e = 0; e < 8; ++e) au[e] = f2bf(xf[e]);
        afr[ks] = __builtin_bit_cast(bf16x8, au);
    }

    f32x4 acc[8];
#pragma unroll
    for (int nt = 0; nt < 8; ++nt) acc[nt] = (f32x4){0.f, 0.f, 0.f, 0.f};

#pragma unroll
    for (int nt = 0; nt < 8; ++nt) {
#pragma unroll
        for (int ks = 0; ks < 4; ++ks) {
            bf16x8 b = wb[(nt * 16 + r) * 16 + ks * 4 + kg];
            acc[nt] = __builtin_amdgcn_mfma_f32_16x16x32_bf16(afr[ks], b, acc[nt], 0, 0, 0);
        }
    }

#pragma unroll
    for (int nt = 0; nt < 8; ++nt) {
#pragma unroll
        for (int reg = 0; reg < 4; ++reg) {
            hbf[(row0 + kg * 4 + reg) * 128 + nt * 16 + r] = f2bf(acc[nt][reg]);
        }
    }
}

// ---------------------------------------------------------------------------
// CSR row offsets from sorted edge_dst via per-node lower_bound.
// ---------------------------------------------------------------------------
__global__ void build_rowptr(const int* __restrict__ dst, int* __restrict__ rowptr) {
    int n = blockIdx.x * blockDim.x + threadIdx.x;
    if (n > NN) return;
    int lo = 0, hi = NE;
    while (lo < hi) {
        int mid = (lo + hi) >> 1;
        if (dst[mid] < n) lo = mid + 1; else hi = mid;
    }
    rowptr[n] = lo;
}

// ---------------------------------------------------------------------------
// One wave per destination node, 4 edges per load instruction.
// Lane l: edge slot q = l>>4, col-quad c = l&15 (cols c*8 .. c*8+7).
// One global_load_dwordx4 gathers 4 full bf16 h-rows (1024 B/wave/instr).
// Edge metadata via wave-uniform scalar loads (no ds_bpermute on the
// critical path). Per-lane 8 fp32 accumulators, statically indexed.
// Final combine: 2 shfl_xor rounds once per wave; q==0 lanes store.
// Each out row written exactly once (covers poisoned d_out).
// ---------------------------------------------------------------------------
__global__ __launch_bounds__(256)
void aggregate(const unsigned int* __restrict__ h32, const float* __restrict__ ew,
               const int* __restrict__ src, const int* __restrict__ rowptr,
               float* __restrict__ out) {
    int wid = (int)((blockIdx.x * 256u + threadIdx.x) >> 6);
    int lane = threadIdx.x & 63;
    if (wid >= NN) return;
    int start = __builtin_amdgcn_readfirstlane(rowptr[wid]);
    int end   = __builtin_amdgcn_readfirstlane(rowptr[wid + 1]);

    int q = lane >> 4;
    int c = lane & 15;

    float acc[8];
#pragma unroll
    for (int j = 0; j < 8; ++j) acc[j] = 0.f;

    const uint4* h4 = (const uint4*)h32;  // [row*16 + c]

    int i = start;
    int nfull = (end - start) >> 2;
#pragma unroll 4
    for (int b = 0; b < nfull; ++b, i += 4) {
        // wave-uniform contiguous metadata -> scalar loads
        int s0 = src[i], s1 = src[i + 1], s2 = src[i + 2], s3 = src[i + 3];
        float w0 = ew[i], w1 = ew[i + 1], w2 = ew[i + 2], w3 = ew[i + 3];
        int   si = q == 0 ? s0 : (q == 1 ? s1 : (q == 2 ? s2 : s3));
        float wi = q == 0 ? w0 : (q == 1 ? w1 : (q == 2 ? w2 : w3));
        uint4 v = h4[(long)si * 16 + c];
        acc[0] += wi * __uint_as_float(v.x << 16);
        acc[1] += wi * __uint_as_float(v.x & 0xFFFF0000u);
        acc[2] += wi * __uint_as_float(v.y << 16);
        acc[3] += wi * __uint_as_float(v.y & 0xFFFF0000u);
        acc[4] += wi * __uint_as_float(v.z << 16);
        acc[5] += wi * __uint_as_float(v.z & 0xFFFF0000u);
        acc[6] += wi * __uint_as_float(v.w << 16);
        acc[7] += wi * __uint_as_float(v.w & 0xFFFF0000u);
    }
    if (i < end) {  // tail group: clamp index, zero weight for q >= g
        int last = end - 1;
        int i1 = i + 1 < end ? i + 1 : last;
        int i2 = i + 2 < end ? i + 2 : last;
        int s0 = src[i], s1 = src[i1], s2 = src[i2];
        float w0 = ew[i];
        float w1 = i + 1 < end ? ew[i1] : 0.f;
        float w2 = i + 2 < end ? ew[i2] : 0.f;
        int   si = q == 0 ? s0 : (q == 1 ? s1 : s2);   // q==3 impossible-valid: reuse s2
        float wi = q == 0 ? w0 : (q == 1 ? w1 : (q == 2 ? w2 : 0.f));
        uint4 v = h4[(long)si * 16 + c];
        acc[0] += wi * __uint_as_float(v.x << 16);
        acc[1] += wi * __uint_as_float(v.x & 0xFFFF0000u);
        acc[2] += wi * __uint_as_float(v.y << 16);
        acc[3] += wi * __uint_as_float(v.y & 0xFFFF0000u);
        acc[4] += wi * __uint_as_float(v.z << 16);
        acc[5] += wi * __uint_as_float(v.z & 0xFFFF0000u);
        acc[6] += wi * __uint_as_float(v.w << 16);
        acc[7] += wi * __uint_as_float(v.w & 0xFFFF0000u);
    }

    // combine edge slots: lanes {l, l^16, l^32, l^48} share the same cols
#pragma unroll
    for (int j = 0; j < 8; ++j) {
        acc[j] += __shfl_xor(acc[j], 16);
        acc[j] += __shfl_xor(acc[j], 32);
    }

    if (q == 0) {
        float4* op = (float4*)(out + (long)wid * 128 + c * 8);
        op[0] = make_float4(acc[0], acc[1], acc[2], acc[3]);
        op[1] = make_float4(acc[4], acc[5], acc[6], acc[7]);
    }
}

extern "C" void kernel_launch(void* const* d_in, const int* in_sizes, int n_in,
                              void* d_out, int out_size, void* d_ws, size_t ws_size,
                              hipStream_t stream) {
    const float* x    = (const float*)d_in[0];
    const float* w    = (const float*)d_in[1];
    const float* ew   = (const float*)d_in[2];
    const int*   esrc = (const int*)d_in[3];
    const int*   edst = (const int*)d_in[4];
    float* out = (float*)d_out;

    unsigned short* hbf = (unsigned short*)d_ws;                       // 25.6 MB
    int* rowptr = (int*)((char*)d_ws + (size_t)NN * 128 * 2);          // +400 KB
    unsigned short* wbf = (unsigned short*)((char*)d_ws + (size_t)NN * 128 * 2 + 400016);

    convert_w<<<64, 256, 0, stream>>>(w, wbf);
    gemm_xwT<<<(NN / 16 + 3) / 4, 256, 0, stream>>>(x, wbf, hbf);
    build_rowptr<<<(NN + 1 + 255) / 256, 256, 0, stream>>>(edst, rowptr);
    aggregate<<<(NN * 64) / 256, 256, 0, stream>>>((const unsigned int*)hbf, ew, esrc, rowptr, out);
}